// Round 1
// baseline (3955.045 us; speedup 1.0000x reference)
//
#include <hip/hip_runtime.h>
#include <math.h>

// Problem constants (from reference: 64x0e + 32x1o + 16x2e -> 64x0e, MLP 64->64->64->64)
constexpr int IRR = 240;        // 64*1 + 32*3 + 16*5
constexpr int HID = 64;
constexpr int WEFF_ROWS = 2744; // 2080 (l0) + 528 (l1) + 136 (l2) symmetric pairs

// ws layout (floats):
//   Weff[2744*64] | A1T[4096] | A2T[4096] | A3T[4096] | dg2[64] | h[n*64] | dh[n*64]
constexpr size_t OFF_WEFF = 0;
constexpr size_t OFF_A1T  = (size_t)WEFF_ROWS * 64;       // 175616
constexpr size_t OFF_A2T  = OFF_A1T + 4096;
constexpr size_t OFF_A3T  = OFF_A2T + 4096;
constexpr size_t OFF_DG2  = OFF_A3T + 4096;
constexpr size_t OFF_H    = OFF_DG2 + 64;

// ---------------------------------------------------------------------------
// prep: build Weff (symmetric-pair-reduced, path-norm folded), transposed MLP
// weights, and dg2 = colsum(A3). Runs every launch (ws is re-poisoned).
// ---------------------------------------------------------------------------
__global__ void prep_kernel(const float* __restrict__ W0, const float* __restrict__ W1,
                            const float* __restrict__ W2, const float* __restrict__ A1,
                            const float* __restrict__ A2, const float* __restrict__ A3,
                            float* __restrict__ weff, float* __restrict__ a1t,
                            float* __restrict__ a2t, float* __restrict__ a3t,
                            float* __restrict__ dg2)
{
    int idx = blockIdx.x * blockDim.x + threadIdx.x;
    const int n_weff = WEFF_ROWS * 64;
    if (idx < n_weff) {
        int row = idx >> 6, k = idx & 63;
        int mul, d, local;
        const float* W;
        if (row < 2080)      { mul = 64; d = 1; local = row;        W = W0; }
        else if (row < 2608) { mul = 32; d = 3; local = row - 2080; W = W1; }
        else                 { mul = 16; d = 5; local = row - 2608; W = W2; }
        // u-major enumeration of (u,v), v>=u: base(u) = u*mul - u*(u-1)/2
        int u = 0;
        while ((u + 1) * mul - (u + 1) * u / 2 <= local) u++;
        int base = u * mul - u * (u - 1) / 2;
        int v = u + (local - base);
        double c = 1.0 / (sqrt(5376.0) * sqrt((double)d)); // PATH_NORM / sqrt(2l+1)
        float wuv = W[(u * mul + v) * 64 + k];
        float val;
        if (u == v) val = (float)c * wuv;
        else        val = (float)c * (wuv + W[(v * mul + u) * 64 + k]);
        weff[(size_t)row * 64 + k] = val;
        return;
    }
    idx -= n_weff;
    if (idx < 3 * 4096) {
        int m = idx >> 12, e = idx & 4095;
        int j = e >> 6, k = e & 63;
        const float* A = (m == 0) ? A1 : (m == 1) ? A2 : A3;
        float* dst     = (m == 0) ? a1t : (m == 1) ? a2t : a3t;
        dst[j * 64 + k] = A[k * 64 + j];   // AT[j][k] = A[k][j]
        return;
    }
    idx -= 3 * 4096;
    if (idx < 64) {
        float s = 0.f;
        for (int k = 0; k < 64; k++) s += A3[k * 64 + idx];
        dg2[idx] = s;
    }
}

// ---------------------------------------------------------------------------
// Forward FCTP, one l-block per launch. Thread = sample; Weff row is
// wave-uniform -> scalar loads; h accumulator in 64 VGPRs.
// ---------------------------------------------------------------------------
template <int MUL, int D, int XOFF, int RB, int INIT>
__global__ __launch_bounds__(64) void fctp_fwd_l(const float* __restrict__ tin,
                                                 const float* __restrict__ weff,
                                                 float* __restrict__ h, int n)
{
    constexpr int LEN = MUL * D;
    constexpr int STR = LEN + 1;           // odd stride -> conflict-free LDS
    __shared__ float xs[64 * STR];
    const int lane = threadIdx.x;
    const int s0 = blockIdx.x * 64;
    const int s = s0 + lane;
    // cooperative, mostly-contiguous staging of this block's x-slab
    for (int idx = lane; idx < 64 * LEN; idx += 64) {
        int ss = idx / LEN, ii = idx - ss * LEN;
        float v = (s0 + ss < n) ? tin[(size_t)(s0 + ss) * IRR + XOFF + ii] : 0.f;
        xs[ss * STR + ii] = v;
    }
    __syncthreads();
    const float* xp = &xs[lane * STR];
    const bool act = s < n;
    float acc[64];
    if (INIT) {
#pragma unroll
        for (int k = 0; k < 64; k++) acc[k] = 0.f;
    } else {
#pragma unroll
        for (int k = 0; k < 64; k++) acc[k] = act ? h[(size_t)s * 64 + k] : 0.f;
    }
    const float* wr = weff + (size_t)RB * 64;
    for (int u = 0; u < MUL; u++) {
        for (int v = u; v < MUL; v++) {
            float P = 0.f;
#pragma unroll
            for (int m = 0; m < D; m++) P += xp[u * D + m] * xp[v * D + m];
#pragma unroll
            for (int k = 0; k < 64; k++) acc[k] += P * wr[k];  // wr[k] uniform -> s_load
            wr += 64;
        }
    }
    if (act) {
#pragma unroll
        for (int k = 0; k < 64; k++) h[(size_t)s * 64 + k] = acc[k];
    }
}

// ---------------------------------------------------------------------------
// Backward FCTP per l-block: dP[p] = <dh, Weff[p]>, scatter into dx (LDS,
// per-thread private row). dh kept in 64 VGPRs.
// ---------------------------------------------------------------------------
template <int MUL, int D, int XOFF, int RB>
__global__ __launch_bounds__(64) void fctp_bwd_l(const float* __restrict__ tin,
                                                 const float* __restrict__ weff,
                                                 const float* __restrict__ dh,
                                                 float* __restrict__ yout, int n)
{
    constexpr int LEN = MUL * D;
    constexpr int STR = 2 * LEN + 1;       // x | dx, odd stride
    __shared__ float lds[64 * STR];
    const int lane = threadIdx.x;
    const int s0 = blockIdx.x * 64;
    const int s = s0 + lane;
    for (int idx = lane; idx < 64 * LEN; idx += 64) {
        int ss = idx / LEN, ii = idx - ss * LEN;
        float v = (s0 + ss < n) ? tin[(size_t)(s0 + ss) * IRR + XOFF + ii] : 0.f;
        lds[ss * STR + ii] = v;
    }
    __syncthreads();
    float* xp = &lds[lane * STR];
    float* dxp = xp + LEN;
    for (int i = 0; i < LEN; i++) dxp[i] = 0.f;
    const bool act = s < n;
    float dhr[64];
#pragma unroll
    for (int k = 0; k < 64; k++) dhr[k] = act ? dh[(size_t)s * 64 + k] : 0.f;
    const float* wr = weff + (size_t)RB * 64;
    for (int u = 0; u < MUL; u++) {
        for (int v = u; v < MUL; v++) {
            float a0 = 0, a1 = 0, a2 = 0, a3 = 0;
#pragma unroll
            for (int k = 0; k < 64; k += 4) {
                a0 += dhr[k] * wr[k];     a1 += dhr[k + 1] * wr[k + 1];
                a2 += dhr[k + 2] * wr[k + 2]; a3 += dhr[k + 3] * wr[k + 3];
            }
            float dp = (a0 + a1) + (a2 + a3);
            wr += 64;
            if (u == v) {
#pragma unroll
                for (int m = 0; m < D; m++) dxp[u * D + m] += 2.f * dp * xp[u * D + m];
            } else {
#pragma unroll
                for (int m = 0; m < D; m++) {
                    float xa = xp[u * D + m], xb = xp[v * D + m];
                    dxp[u * D + m] += dp * xb;
                    dxp[v * D + m] += dp * xa;
                }
            }
        }
    }
    if (act) {
        for (int i = 0; i < LEN; i++) yout[(size_t)s * IRR + XOFF + i] = dxp[i];
    }
}

// ---------------------------------------------------------------------------
// MLP forward + backward. Thread = sample. Runtime-indexed activations live in
// two 64-float LDS slots; compile-time-indexed ones in VGPR arrays. All matrix
// reads are wave-uniform rows of the transposed matrices -> scalar loads.
// ---------------------------------------------------------------------------
__global__ __launch_bounds__(64) void mlp_kernel(const float* __restrict__ h,
                                                 const float* __restrict__ A1T,
                                                 const float* __restrict__ A2T,
                                                 const float* __restrict__ A3T,
                                                 const float* __restrict__ b1,
                                                 const float* __restrict__ b2,
                                                 const float* __restrict__ b3,
                                                 const float* __restrict__ dg2,
                                                 float* __restrict__ xout,
                                                 float* __restrict__ dhout, int n)
{
    __shared__ float lds[64 * 129];
    const int lane = threadIdx.x;
    const int s = blockIdx.x * 64 + lane;
    const bool act = s < n;
    float* sA = &lds[lane * 129];   // holds h, then z1, then dz1
    float* sB = sA + 64;            // holds g1, then g2
#pragma unroll
    for (int k = 0; k < 64; k++) sA[k] = act ? h[(size_t)s * 64 + k] : 0.f;
    float zk[64], z2v[64];
    // z1 = h @ A1.T + b1
#pragma unroll
    for (int k = 0; k < 64; k++) zk[k] = b1[k];
    for (int j = 0; j < 64; j++) {
        float hj = sA[j];
        const float* Ar = A1T + j * 64;
#pragma unroll
        for (int k = 0; k < 64; k++) zk[k] += Ar[k] * hj;
    }
#pragma unroll
    for (int k = 0; k < 64; k++) {
        float z = zk[k], sg = 1.f / (1.f + __expf(-z));
        sA[k] = z; sB[k] = z * sg;          // store z1, g1
    }
    // z2 = g1 @ A2.T + b2
#pragma unroll
    for (int k = 0; k < 64; k++) z2v[k] = b2[k];
    for (int j = 0; j < 64; j++) {
        float gj = sB[j];
        const float* Ar = A2T + j * 64;
#pragma unroll
        for (int k = 0; k < 64; k++) z2v[k] += Ar[k] * gj;
    }
#pragma unroll
    for (int k = 0; k < 64; k++) {
        float z = z2v[k], sg = 1.f / (1.f + __expf(-z));
        sB[k] = z * sg;                      // g2 (z2 stays in VGPRs)
    }
    // x = g2 @ A3.T + b3
#pragma unroll
    for (int k = 0; k < 64; k++) zk[k] = b3[k];
    for (int j = 0; j < 64; j++) {
        float gj = sB[j];
        const float* Ar = A3T + j * 64;
#pragma unroll
        for (int k = 0; k < 64; k++) zk[k] += Ar[k] * gj;
    }
    if (act) {
#pragma unroll
        for (int k = 0; k < 64; k++) xout[(size_t)s * 64 + k] = zk[k];
    }
    // dz2 = dg2 * silu'(z2)   (cotangent on x is all-ones; dg2 = colsum(A3))
#pragma unroll
    for (int k = 0; k < 64; k++) {
        float z = z2v[k], sg = 1.f / (1.f + __expf(-z));
        z2v[k] = dg2[k] * sg * (1.f + z * (1.f - sg));
    }
    // dz1[j] = (dz2 . A2T-row-j) * silu'(z1[j])   -> overwrite sA
    for (int j = 0; j < 64; j++) {
        float a0 = 0, a1 = 0, a2 = 0, a3 = 0;
        const float* Ar = A2T + j * 64;
#pragma unroll
        for (int k = 0; k < 64; k += 4) {
            a0 += z2v[k] * Ar[k];     a1 += z2v[k + 1] * Ar[k + 1];
            a2 += z2v[k + 2] * Ar[k + 2]; a3 += z2v[k + 3] * Ar[k + 3];
        }
        float dg1 = (a0 + a1) + (a2 + a3);
        float z = sA[j], sg = 1.f / (1.f + __expf(-z));
        sA[j] = dg1 * sg * (1.f + z * (1.f - sg));
    }
#pragma unroll
    for (int k = 0; k < 64; k++) zk[k] = sA[k];   // dz1 -> VGPRs
    // dh[j] = dz1 . A1T-row-j
    for (int j = 0; j < 64; j++) {
        float a0 = 0, a1 = 0, a2 = 0, a3 = 0;
        const float* Ar = A1T + j * 64;
#pragma unroll
        for (int k = 0; k < 64; k += 4) {
            a0 += zk[k] * Ar[k];     a1 += zk[k + 1] * Ar[k + 1];
            a2 += zk[k + 2] * Ar[k + 2]; a3 += zk[k + 3] * Ar[k + 3];
        }
        if (act) dhout[(size_t)s * 64 + j] = (a0 + a1) + (a2 + a3);
    }
}

// ---------------------------------------------------------------------------
extern "C" void kernel_launch(void* const* d_in, const int* in_sizes, int n_in,
                              void* d_out, int out_size, void* d_ws, size_t ws_size,
                              hipStream_t stream)
{
    const float* tin = (const float*)d_in[0];
    const float* W0  = (const float*)d_in[1];
    const float* W1  = (const float*)d_in[2];
    const float* W2  = (const float*)d_in[3];
    const float* A1  = (const float*)d_in[4];
    const float* b1  = (const float*)d_in[5];
    const float* A2  = (const float*)d_in[6];
    const float* b2  = (const float*)d_in[7];
    const float* A3  = (const float*)d_in[8];
    const float* b3  = (const float*)d_in[9];
    float* out = (float*)d_out;
    float* ws  = (float*)d_ws;
    const int n = in_sizes[0] / IRR;       // 50000

    float* weff = ws + OFF_WEFF;
    float* a1t  = ws + OFF_A1T;
    float* a2t  = ws + OFF_A2T;
    float* a3t  = ws + OFF_A3T;
    float* dg2  = ws + OFF_DG2;
    float* h    = ws + OFF_H;
    float* dh   = h + (size_t)n * 64;
    float* xout = out;
    float* yout = out + (size_t)n * 64;

    const int total_prep = WEFF_ROWS * 64 + 3 * 4096 + 64;
    prep_kernel<<<(total_prep + 255) / 256, 256, 0, stream>>>(W0, W1, W2, A1, A2, A3,
                                                              weff, a1t, a2t, a3t, dg2);
    const int nb = (n + 63) / 64;
    fctp_fwd_l<64, 1,   0,    0, 1><<<nb, 64, 0, stream>>>(tin, weff, h, n);
    fctp_fwd_l<32, 3,  64, 2080, 0><<<nb, 64, 0, stream>>>(tin, weff, h, n);
    fctp_fwd_l<16, 5, 160, 2608, 0><<<nb, 64, 0, stream>>>(tin, weff, h, n);
    mlp_kernel<<<nb, 64, 0, stream>>>(h, a1t, a2t, a3t, b1, b2, b3, dg2, xout, dh, n);
    fctp_bwd_l<64, 1,   0,    0><<<nb, 64, 0, stream>>>(tin, weff, dh, yout, n);
    fctp_bwd_l<32, 3,  64, 2080><<<nb, 64, 0, stream>>>(tin, weff, dh, yout, n);
    fctp_bwd_l<16, 5, 160, 2608><<<nb, 64, 0, stream>>>(tin, weff, dh, yout, n);
}

// Round 2
// 866.431 us; speedup vs baseline: 4.5648x; 4.5648x over previous
//
#include <hip/hip_runtime.h>
#include <math.h>

// ---------------------------------------------------------------------------
// Problem: FCTP(64x0e+32x1o+16x2e -> 64x0e) + 3-layer SiLU MLP, fwd + input-grad.
// Restructure: FCTP fwd = P[N,2744] @ Weff[2744,64]  (P = sym pair dots)
//              FCTP bwd = dh[N,64] @ Wbsym[64,5376] -> row-dot reduce vs x
// Both GEMMs on bf16 MFMA 16x16x32, 64-sample tiles, K-chunks of 64 in LDS.
// ---------------------------------------------------------------------------

typedef short bf8 __attribute__((ext_vector_type(8)));          // 8 bf16 (bits)
typedef float f4 __attribute__((ext_vector_type(4)));
typedef unsigned short u16x4 __attribute__((ext_vector_type(4)));

constexpr int IRR = 240;

// ws layout (bytes, all 256-aligned)
constexpr size_t B_WTF = 0;                 // bf16 [64 chan][2752 pair]  fwd B^T
constexpr size_t B_WB  = 352256;            // bf16 [5376 pair][64 chan]  bwd B
constexpr size_t B_PT  = 1040384;           // int4 [2752] pair table (uoff,voff,d,0)
constexpr size_t B_A1T = 1084416;           // f32 [64][64]
constexpr size_t B_A2T = 1100800;
constexpr size_t B_A3T = 1117184;
constexpr size_t B_DG2 = 1133568;           // f32 [64]
constexpr size_t B_H   = 1133824;           // f32 [n][64], then dh after

__device__ inline unsigned short f2bf(float x) {
    unsigned int u = __float_as_uint(x);
    unsigned int r = (u + 0x7fffu + ((u >> 16) & 1u)) >> 16;
    return (unsigned short)r;
}
__device__ inline float bf2f(unsigned short u) {
    return __uint_as_float(((unsigned int)u) << 16);
}

// decode symmetric pair id p (u-major, v>=u) -> (l,u,v,mul)
__device__ inline void dec_sym(int p, int& l, int& u, int& v, int& mul) {
    int local;
    if (p < 2080)      { l = 0; mul = 64; local = p; }
    else if (p < 2608) { l = 1; mul = 32; local = p - 2080; }
    else               { l = 2; mul = 16; local = p - 2608; }
    int uu = 0;
    while ((uu + 1) * mul - (uu + 1) * uu / 2 <= local) uu++;
    int base = uu * mul - uu * (uu - 1) / 2;
    u = uu; v = uu + (local - base);
}

// ---------------------------------------------------------------------------
__global__ void prep_kernel(const float* __restrict__ W0, const float* __restrict__ W1,
                            const float* __restrict__ W2, const float* __restrict__ A1,
                            const float* __restrict__ A2, const float* __restrict__ A3,
                            unsigned short* __restrict__ wtf, unsigned short* __restrict__ wb,
                            int4* __restrict__ ptab, float* __restrict__ a1t,
                            float* __restrict__ a2t, float* __restrict__ a3t,
                            float* __restrict__ dg2)
{
    int idx = blockIdx.x * blockDim.x + threadIdx.x;
    const double c0 = 1.0 / sqrt(5376.0);
    const double cl_[3] = { c0, c0 / sqrt(3.0), c0 / sqrt(5.0) };
    // A) wtf[chan][2752]
    if (idx < 64 * 2752) {
        int c = idx / 2752, p = idx - c * 2752;
        unsigned short val = 0;
        if (p < 2744) {
            int l, u, v, mul; dec_sym(p, l, u, v, mul);
            const float* W = (l == 0) ? W0 : (l == 1) ? W1 : W2;
            float wv = W[(u * mul + v) * 64 + c];
            if (u != v) wv += W[(v * mul + u) * 64 + c];
            val = f2bf((float)(cl_[l] * wv));
        }
        wtf[c * 2752 + p] = val;
        return;
    }
    idx -= 64 * 2752;
    // B) wb[5376][64] : full symmetrized (diag doubled)
    if (idx < 5376 * 64) {
        int pair = idx >> 6, c = idx & 63;
        int l, w, v, mul;
        if (pair < 4096)      { l = 0; mul = 64; w = pair >> 6;          v = pair & 63; }
        else if (pair < 5120) { l = 1; mul = 32; w = (pair - 4096) >> 5; v = (pair - 4096) & 31; }
        else                  { l = 2; mul = 16; w = (pair - 5120) >> 4; v = (pair - 5120) & 15; }
        const float* W = (l == 0) ? W0 : (l == 1) ? W1 : W2;
        float val;
        if (v == w) val = (float)(2.0 * cl_[l]) * W[(w * mul + w) * 64 + c];
        else        val = (float)cl_[l] * (W[(w * mul + v) * 64 + c] + W[(v * mul + w) * 64 + c]);
        wb[(size_t)pair * 64 + c] = f2bf(val);
        return;
    }
    idx -= 5376 * 64;
    // C) ptab
    if (idx < 2752) {
        int4 t = make_int4(0, 0, 0, 0);
        if (idx < 2744) {
            int l, u, v, mul; dec_sym(idx, l, u, v, mul);
            int d = 2 * l + 1;
            int base = (l == 0) ? 0 : (l == 1) ? 64 : 160;
            t = make_int4(base + u * d, base + v * d, d, 0);
        }
        ptab[idx] = t;
        return;
    }
    idx -= 2752;
    // D) transposed MLP mats
    if (idx < 3 * 4096) {
        int m = idx >> 12, e = idx & 4095;
        int j = e >> 6, k = e & 63;
        const float* A = (m == 0) ? A1 : (m == 1) ? A2 : A3;
        float* dst     = (m == 0) ? a1t : (m == 1) ? a2t : a3t;
        dst[j * 64 + k] = A[k * 64 + j];
        return;
    }
    idx -= 3 * 4096;
    // E) dg2 = colsum(A3)
    if (idx < 64) {
        float sacc = 0.f;
        for (int k = 0; k < 64; k++) sacc += A3[k * 64 + idx];
        dg2[idx] = sacc;
    }
}

// ---------------------------------------------------------------------------
// Forward FCTP: per block 64 samples, 4 waves. 43 K-chunks of 64 pairs.
// A = P (computed in fp32 from LDS x-slab, stored bf16 XOR-swizzled),
// B = wtf chunk (staged swizzled). C = h[64x64] fp32.
// ---------------------------------------------------------------------------
__global__ __launch_bounds__(256) void fctp_fwd_mfma(
    const float* __restrict__ tin, const unsigned short* __restrict__ wtf,
    const int4* __restrict__ ptab, float* __restrict__ h, int n)
{
    __shared__ float xs[64][241];
    __shared__ unsigned short Pb[64][64];
    __shared__ unsigned short Wt[64][64];
    const int tid  = threadIdx.x;
    const int wv   = tid >> 6;
    const int l15  = tid & 15;
    const int quad = (tid & 63) >> 4;
    const int s0   = blockIdx.x * 64;
    // stage x-slab (fp32)
    for (int i = tid; i < 64 * 60; i += 256) {
        int ss = i / 60, q = i - ss * 60;
        float4 v = make_float4(0.f, 0.f, 0.f, 0.f);
        if (s0 + ss < n) v = ((const float4*)(tin + (size_t)(s0 + ss) * IRR))[q];
        xs[ss][4 * q + 0] = v.x; xs[ss][4 * q + 1] = v.y;
        xs[ss][4 * q + 2] = v.z; xs[ss][4 * q + 3] = v.w;
    }
    __syncthreads();
    f4 acc[4];
    #pragma unroll
    for (int t = 0; t < 4; t++) acc[t] = (f4){0.f, 0.f, 0.f, 0.f};
    const int sA   = 16 * wv + l15;       // A-frag row (sample)
    const int prow = tid & 63;            // P-compute sample
    const int pg   = tid >> 6;            // P-compute pair group
    #pragma unroll 1
    for (int ch = 0; ch < 43; ++ch) {
        const int p0 = ch * 64;
        // stage Wt chunk (swizzled): q -> (chan, octet)
        {
            int q = tid * 2;
            #pragma unroll
            for (int it = 0; it < 2; ++it) {
                int c = (q + it) >> 3, o = (q + it) & 7;
                bf8 w = *(const bf8*)(wtf + c * 2752 + p0 + o * 8);
                *(bf8*)&Wt[c][(o ^ (c & 7)) * 8] = w;
            }
        }
        // P compute: 16 pairs per thread (wave-uniform pair ids -> s_loads)
        {
            unsigned short tmp[16];
            #pragma unroll
            for (int j = 0; j < 16; ++j) {
                int4 tb = ptab[p0 + pg * 16 + j];
                float P = 0.f;
                for (int m = 0; m < tb.z; ++m)
                    P += xs[prow][tb.x + m] * xs[prow][tb.y + m];
                tmp[j] = f2bf(P);
            }
            bf8 v0, v1;
            #pragma unroll
            for (int j = 0; j < 8; ++j) { v0[j] = (short)tmp[j]; v1[j] = (short)tmp[8 + j]; }
            int o0 = pg * 2;
            *(bf8*)&Pb[prow][(o0 ^ (prow & 7)) * 8]       = v0;
            *(bf8*)&Pb[prow][((o0 + 1) ^ (prow & 7)) * 8] = v1;
        }
        __syncthreads();
        #pragma unroll
        for (int k = 0; k < 2; ++k) {
            int oct = k * 4 + quad;
            bf8 a = *(const bf8*)&Pb[sA][(oct ^ (sA & 7)) * 8];
            #pragma unroll
            for (int t = 0; t < 4; ++t) {
                int c = t * 16 + l15;
                bf8 b = *(const bf8*)&Wt[c][(oct ^ (c & 7)) * 8];
                acc[t] = __builtin_amdgcn_mfma_f32_16x16x32_bf16(a, b, acc[t], 0, 0, 0);
            }
        }
        __syncthreads();
    }
    // write h: C row = 16wv + quad*4 + r, col = 16t + l15
    const int srow = 16 * wv + quad * 4;
    #pragma unroll
    for (int t = 0; t < 4; ++t)
        #pragma unroll
        for (int r = 0; r < 4; ++r) {
            int s = s0 + srow + r;
            if (s < n) h[(size_t)s * 64 + t * 16 + l15] = acc[t][r];
        }
}

// ---------------------------------------------------------------------------
// Backward FCTP: dP chunk = dh[64x64] @ Wb_chunk[64x64], then row-dot vs x
// (shuffle-reduce over 16 lanes), staged to dxb, flushed coalesced to y.
// Chunks: 0..63 l0 (w=ch), 64..79 l1 (2 w/chunk), 80..83 l2 (4 w/chunk).
// ---------------------------------------------------------------------------
__global__ __launch_bounds__(256) void fctp_bwd_mfma(
    const float* __restrict__ tin, const unsigned short* __restrict__ wb,
    const float* __restrict__ dh, float* __restrict__ y, int n)
{
    __shared__ unsigned short xT[240][68];
    __shared__ unsigned short dhb[64][64];
    __shared__ unsigned short Wc[64][64];
    __shared__ float dxb[64][81];
    const int tid  = threadIdx.x;
    const int wv   = tid >> 6;
    const int l15  = tid & 15;
    const int quad = (tid & 63) >> 4;
    const int s0   = blockIdx.x * 64;
    // stage dh (bf16, swizzled) — zero-fill pad samples
    {
        int q = tid * 2;
        #pragma unroll
        for (int it = 0; it < 2; ++it) {
            int ss = (q + it) >> 3, o = (q + it) & 7;
            float4 v0 = make_float4(0.f, 0.f, 0.f, 0.f), v1 = v0;
            if (s0 + ss < n) {
                const float4* p = (const float4*)(dh + (size_t)(s0 + ss) * 64 + o * 8);
                v0 = p[0]; v1 = p[1];
            }
            bf8 w;
            w[0] = (short)f2bf(v0.x); w[1] = (short)f2bf(v0.y);
            w[2] = (short)f2bf(v0.z); w[3] = (short)f2bf(v0.w);
            w[4] = (short)f2bf(v1.x); w[5] = (short)f2bf(v1.y);
            w[6] = (short)f2bf(v1.z); w[7] = (short)f2bf(v1.w);
            *(bf8*)&dhb[ss][(o ^ (ss & 7)) * 8] = w;
        }
    }
    // stage x transposed (bf16)
    for (int i = tid; i < 64 * 60; i += 256) {
        int ss = i / 60, q = i - ss * 60;
        float4 v = make_float4(0.f, 0.f, 0.f, 0.f);
        if (s0 + ss < n) v = ((const float4*)(tin + (size_t)(s0 + ss) * IRR))[q];
        xT[4 * q + 0][ss] = f2bf(v.x); xT[4 * q + 1][ss] = f2bf(v.y);
        xT[4 * q + 2][ss] = f2bf(v.z); xT[4 * q + 3][ss] = f2bf(v.w);
    }
    __syncthreads();
    // persistent A-frags (dh)
    const int arow = 16 * wv + l15;
    bf8 af0 = *(const bf8*)&dhb[arow][((0 + quad) ^ (arow & 7)) * 8];
    bf8 af1 = *(const bf8*)&dhb[arow][((4 + quad) ^ (arow & 7)) * 8];
    const int srow = 16 * wv + quad * 4;
    #pragma unroll 1
    for (int ch = 0; ch < 84; ++ch) {
        // stage Wb chunk
        {
            int q = tid * 2;
            #pragma unroll
            for (int it = 0; it < 2; ++it) {
                int pr = (q + it) >> 3, o = (q + it) & 7;
                bf8 w = *(const bf8*)(wb + (size_t)(ch * 64 + pr) * 64 + o * 8);
                *(bf8*)&Wc[pr][(o ^ (pr & 7)) * 8] = w;
            }
        }
        __syncthreads();
        f4 dp[4];
        #pragma unroll
        for (int t = 0; t < 4; t++) dp[t] = (f4){0.f, 0.f, 0.f, 0.f};
        #pragma unroll
        for (int k = 0; k < 2; ++k) {
            int oct = k * 4 + quad;
            bf8 a = k ? af1 : af0;
            #pragma unroll
            for (int t = 0; t < 4; ++t) {
                int pr = t * 16 + l15;
                bf8 b = *(const bf8*)&Wc[pr][(oct ^ (pr & 7)) * 8];
                dp[t] = __builtin_amdgcn_mfma_f32_16x16x32_bf16(a, b, dp[t], 0, 0, 0);
            }
        }
        // consume dP: dp[t][r] = dP[sample srow+r][pair 16t+l15]
        if (ch < 64) {                       // l0: w = ch, v = 16t + l15
            float part[4] = {0.f, 0.f, 0.f, 0.f};
            #pragma unroll
            for (int t = 0; t < 4; ++t) {
                int vv = t * 16 + l15;
                u16x4 x4 = *(const u16x4*)&xT[vv][srow];
                #pragma unroll
                for (int r = 0; r < 4; ++r) part[r] += dp[t][r] * bf2f(x4[r]);
            }
            #pragma unroll
            for (int m = 1; m < 16; m <<= 1)
                #pragma unroll
                for (int r = 0; r < 4; ++r) part[r] += __shfl_xor(part[r], m);
            if (l15 == 0) {
                #pragma unroll
                for (int r = 0; r < 4; ++r) dxb[srow + r][ch & 15] = part[r];
            }
        } else if (ch < 80) {                // l1: w = 2*c1 + (t>>1), v = 16*(t&1)+l15
            int c1 = ch - 64;
            float res[2][3][4];
            #pragma unroll
            for (int wi = 0; wi < 2; wi++)
                #pragma unroll
                for (int m = 0; m < 3; m++)
                    #pragma unroll
                    for (int r = 0; r < 4; r++) res[wi][m][r] = 0.f;
            #pragma unroll
            for (int t = 0; t < 4; ++t) {
                int wi = t >> 1, vloc = (t & 1) * 16 + l15;
                #pragma unroll
                for (int m = 0; m < 3; ++m) {
                    int irr = 64 + vloc * 3 + m;
                    u16x4 x4 = *(const u16x4*)&xT[irr][srow];
                    #pragma unroll
                    for (int r = 0; r < 4; ++r) res[wi][m][r] += dp[t][r] * bf2f(x4[r]);
                }
            }
            #pragma unroll
            for (int mm = 1; mm < 16; mm <<= 1)
                #pragma unroll
                for (int wi = 0; wi < 2; wi++)
                    #pragma unroll
                    for (int m = 0; m < 3; m++)
                        #pragma unroll
                        for (int r = 0; r < 4; r++)
                            res[wi][m][r] += __shfl_xor(res[wi][m][r], mm);
            if (l15 == 0) {
                #pragma unroll
                for (int wi = 0; wi < 2; wi++)
                    #pragma unroll
                    for (int m = 0; m < 3; m++)
                        #pragma unroll
                        for (int r = 0; r < 4; r++)
                            dxb[srow + r][(c1 & 7) * 6 + wi * 3 + m] = res[wi][m][r];
            }
        } else {                             // l2: w = 4*c2 + t, v = l15
            int c2 = ch - 80;
            #pragma unroll
            for (int t = 0; t < 4; ++t) {
                float rs[5][4];
                #pragma unroll
                for (int m = 0; m < 5; ++m) {
                    int irr = 160 + l15 * 5 + m;
                    u16x4 x4 = *(const u16x4*)&xT[irr][srow];
                    #pragma unroll
                    for (int r = 0; r < 4; ++r) rs[m][r] = dp[t][r] * bf2f(x4[r]);
                }
                #pragma unroll
                for (int mm = 1; mm < 16; mm <<= 1)
                    #pragma unroll
                    for (int m = 0; m < 5; m++)
                        #pragma unroll
                        for (int r = 0; r < 4; r++) rs[m][r] += __shfl_xor(rs[m][r], mm);
                if (l15 == 0) {
                    #pragma unroll
                    for (int m = 0; m < 5; m++)
                        #pragma unroll
                        for (int r = 0; r < 4; r++)
                            dxb[srow + r][c2 * 20 + t * 5 + m] = rs[m][r];
                }
            }
        }
        __syncthreads();
        // flushes (uniform conditions)
        if (ch == 15 || ch == 31 || ch == 47 || ch == 63) {
            int w0 = ch - 15;
            for (int i = tid; i < 64 * 4; i += 256) {
                int ss = i >> 2, c4 = (i & 3) * 4;
                if (s0 + ss < n) {
                    float4 v = make_float4(dxb[ss][c4], dxb[ss][c4 + 1],
                                           dxb[ss][c4 + 2], dxb[ss][c4 + 3]);
                    *(float4*)(y + (size_t)(s0 + ss) * IRR + w0 + c4) = v;
                }
            }
            __syncthreads();
        } else if (ch == 71 || ch == 79) {
            int base = (ch == 71) ? 64 : 112;
            for (int i = tid; i < 64 * 12; i += 256) {
                int ss = i / 12, c4 = (i - ss * 12) * 4;
                if (s0 + ss < n) {
                    float4 v = make_float4(dxb[ss][c4], dxb[ss][c4 + 1],
                                           dxb[ss][c4 + 2], dxb[ss][c4 + 3]);
                    *(float4*)(y + (size_t)(s0 + ss) * IRR + base + c4) = v;
                }
            }
            __syncthreads();
        } else if (ch == 83) {
            for (int i = tid; i < 64 * 20; i += 256) {
                int ss = i / 20, c4 = (i - ss * 20) * 4;
                if (s0 + ss < n) {
                    float4 v = make_float4(dxb[ss][c4], dxb[ss][c4 + 1],
                                           dxb[ss][c4 + 2], dxb[ss][c4 + 3]);
                    *(float4*)(y + (size_t)(s0 + ss) * IRR + 160 + c4) = v;
                }
            }
        }
    }
}

// ---------------------------------------------------------------------------
// MLP fwd+bwd, thread-per-sample, 128 thr/block. All matvec inner indices are
// register-static; activations in fp32 LDS column stash (per-thread private —
// no syncs needed). z1 stashed bf16 (only affects silu' in bwd).
// ---------------------------------------------------------------------------
__global__ __launch_bounds__(128) void mlp_kernel(
    const float* __restrict__ h, const float* __restrict__ A1,
    const float* __restrict__ A2, const float* __restrict__ a1t,
    const float* __restrict__ a2t, const float* __restrict__ a3t,
    const float* __restrict__ b1, const float* __restrict__ b2,
    const float* __restrict__ b3, const float* __restrict__ dg2,
    float* __restrict__ xout, float* __restrict__ dhout, int n)
{
    __shared__ float hst[64][128];
    __shared__ unsigned short z1b[64][128];
    const int tid = threadIdx.x;
    const int s = blockIdx.x * 128 + tid;
    const bool act = s < n;
    #pragma unroll
    for (int q = 0; q < 16; ++q) {
        float4 v = make_float4(0.f, 0.f, 0.f, 0.f);
        if (act) v = ((const float4*)(h + (size_t)s * 64))[q];
        hst[4 * q + 0][tid] = v.x; hst[4 * q + 1][tid] = v.y;
        hst[4 * q + 2][tid] = v.z; hst[4 * q + 3][tid] = v.w;
    }
    float acc[64];
    // z1 = h @ A1T (scatter form: j rolled, k static)
    #pragma unroll
    for (int k = 0; k < 64; ++k) acc[k] = b1[k];
    #pragma unroll 4
    for (int j = 0; j < 64; ++j) {
        float hj = hst[j][tid];
        const float* r = a1t + j * 64;
        #pragma unroll
        for (int k = 0; k < 64; ++k) acc[k] += hj * r[k];
    }
    #pragma unroll
    for (int k = 0; k < 64; ++k) {
        float z = acc[k];
        z1b[k][tid] = f2bf(z);
        float sg = 1.f / (1.f + __expf(-z));
        hst[k][tid] = z * sg;                       // g1
    }
    // z2
    #pragma unroll
    for (int k = 0; k < 64; ++k) acc[k] = b2[k];
    #pragma unroll 4
    for (int j = 0; j < 64; ++j) {
        float gj = hst[j][tid];
        const float* r = a2t + j * 64;
        #pragma unroll
        for (int k = 0; k < 64; ++k) acc[k] += gj * r[k];
    }
    float z2r[64];
    #pragma unroll
    for (int k = 0; k < 64; ++k) {
        z2r[k] = acc[k];
        float sg = 1.f / (1.f + __expf(-acc[k]));
        hst[k][tid] = acc[k] * sg;                  // g2
    }
    // x = g2 @ A3T + b3
    #pragma unroll
    for (int k = 0; k < 64; ++k) acc[k] = b3[k];
    #pragma unroll 4
    for (int j = 0; j < 64; ++j) {
        float gj = hst[j][tid];
        const float* r = a3t + j * 64;
        #pragma unroll
        for (int k = 0; k < 64; ++k) acc[k] += gj * r[k];
    }
    if (act) {
        float4* xo = (float4*)(xout + (size_t)s * 64);
        #pragma unroll
        for (int q = 0; q < 16; ++q)
            xo[q] = make_float4(acc[4 * q], acc[4 * q + 1], acc[4 * q + 2], acc[4 * q + 3]);
    }
    // dz2 = dg2 * silu'(z2)  -> stash fp32
    #pragma unroll
    for (int k = 0; k < 64; ++k) {
        float z = z2r[k];
        float sg = 1.f / (1.f + __expf(-z));
        hst[k][tid] = dg2[k] * sg * (1.f + z * (1.f - sg));
    }
    // dg1[j] = sum_k dz2_k * A2[k][j]  (scatter form over raw A2 rows)
    #pragma unroll
    for (int j = 0; j < 64; ++j) acc[j] = 0.f;
    #pragma unroll 4
    for (int k = 0; k < 64; ++k) {
        float d = hst[k][tid];
        const float* r = A2 + k * 64;
        #pragma unroll
        for (int j = 0; j < 64; ++j) acc[j] += d * r[j];
    }
    // dz1 = dg1 * silu'(z1)  -> stash fp32
    #pragma unroll
    for (int j = 0; j < 64; ++j) {
        float z = bf2f(z1b[j][tid]);
        float sg = 1.f / (1.f + __expf(-z));
        hst[j][tid] = acc[j] * sg * (1.f + z * (1.f - sg));
    }
    // dh[j] = sum_k dz1_k * A1[k][j]
    #pragma unroll
    for (int j = 0; j < 64; ++j) acc[j] = 0.f;
    #pragma unroll 4
    for (int k = 0; k < 64; ++k) {
        float d = hst[k][tid];
        const float* r = A1 + k * 64;
        #pragma unroll
        for (int j = 0; j < 64; ++j) acc[j] += d * r[j];
    }
    if (act) {
        float4* dho = (float4*)(dhout + (size_t)s * 64);
        #pragma unroll
        for (int q = 0; q < 16; ++q)
            dho[q] = make_float4(acc[4 * q], acc[4 * q + 1], acc[4 * q + 2], acc[4 * q + 3]);
    }
}

// ---------------------------------------------------------------------------
extern "C" void kernel_launch(void* const* d_in, const int* in_sizes, int n_in,
                              void* d_out, int out_size, void* d_ws, size_t ws_size,
                              hipStream_t stream)
{
    const float* tin = (const float*)d_in[0];
    const float* W0  = (const float*)d_in[1];
    const float* W1  = (const float*)d_in[2];
    const float* W2  = (const float*)d_in[3];
    const float* A1  = (const float*)d_in[4];
    const float* b1  = (const float*)d_in[5];
    const float* A2  = (const float*)d_in[6];
    const float* b2  = (const float*)d_in[7];
    const float* A3  = (const float*)d_in[8];
    const float* b3  = (const float*)d_in[9];
    float* out = (float*)d_out;
    char* ws   = (char*)d_ws;
    const int n = in_sizes[0] / IRR;

    unsigned short* wtf = (unsigned short*)(ws + B_WTF);
    unsigned short* wb  = (unsigned short*)(ws + B_WB);
    int4*  ptab = (int4*)(ws + B_PT);
    float* a1t  = (float*)(ws + B_A1T);
    float* a2t  = (float*)(ws + B_A2T);
    float* a3t  = (float*)(ws + B_A3T);
    float* dg2  = (float*)(ws + B_DG2);
    float* h    = (float*)(ws + B_H);
    float* dh   = h + (size_t)n * 64;
    float* xout = out;
    float* yout = out + (size_t)n * 64;

    prep_kernel<<<2091, 256, 0, stream>>>(W0, W1, W2, A1, A2, A3,
                                          wtf, wb, ptab, a1t, a2t, a3t, dg2);
    const int nb64 = (n + 63) / 64;
    fctp_fwd_mfma<<<nb64, 256, 0, stream>>>(tin, wtf, ptab, h, n);
    mlp_kernel<<<(n + 127) / 128, 128, 0, stream>>>(h, A1, A2, a1t, a2t, a3t,
                                                    b1, b2, b3, dg2, xout, dh, n);
    fctp_bwd_mfma<<<nb64, 256, 0, stream>>>(tin, wb, dh, yout, n);
}

// Round 4
// 465.955 us; speedup vs baseline: 8.4880x; 1.8595x over previous
//
#include <hip/hip_runtime.h>
#include <math.h>
#include <utility>

// ---------------------------------------------------------------------------
// FCTP(64x0e+32x1o+16x2e -> 64x0e) + 3-layer SiLU MLP, fwd + input-grad.
//   fwd: h = P[N,2880pad] @ Weff[2880,64], P computed in-registers (static pairs)
//   bwd: dP^T = Wb_chunk[64pair,64ch] @ dh^T[64ch,64s] (A from global, B persistent)
//        then thread-per-sample row-dot vs x (fp32 regs, static indices)
// Single-wave blocks (64 thr = 64 samples): barriers are wave-internal (~free).
// ---------------------------------------------------------------------------

typedef short bf8 __attribute__((ext_vector_type(8)));
typedef float f4 __attribute__((ext_vector_type(4)));

constexpr int IRR = 240;

// padded fwd pair enumeration: l0: [0,2112) real 2080 ; l1: [2112,2688) real 528
// l2: [2688,2880) real 136.  45 chunks of 64.
constexpr int NP = 2880;

struct PTab { short u[NP]; short v[NP]; signed char l[NP]; };
constexpr PTab build_ptab() {
    PTab t{}; int p = 0;
    for (int u = 0; u < 64; u++) for (int v = u; v < 64; v++) { t.u[p]=(short)u; t.v[p]=(short)v; t.l[p]=0; p++; }
    while (p < 2112) { t.l[p] = -1; p++; }
    for (int u = 0; u < 32; u++) for (int v = u; v < 32; v++) { t.u[p]=(short)u; t.v[p]=(short)v; t.l[p]=1; p++; }
    while (p < 2688) { t.l[p] = -1; p++; }
    for (int u = 0; u < 16; u++) for (int v = u; v < 16; v++) { t.u[p]=(short)u; t.v[p]=(short)v; t.l[p]=2; p++; }
    while (p < NP)   { t.l[p] = -1; p++; }
    return t;
}
constexpr PTab PT = build_ptab();

// ws layout (bytes)
constexpr size_t B_WTF = 0;                       // bf16 [64 chan][2880 pair]
constexpr size_t B_WB  = (size_t)64 * NP * 2;     // 368640 : bf16 [5376 pair][64 chan]
constexpr size_t B_A1T = B_WB + (size_t)5376 * 64 * 2;   // 1056768
constexpr size_t B_A2T = B_A1T + 16384;
constexpr size_t B_A3T = B_A2T + 16384;
constexpr size_t B_DG2 = B_A3T + 16384;
constexpr size_t B_H   = B_DG2 + 256;

__device__ __forceinline__ unsigned short f2bf(float x) {
    unsigned int u = __float_as_uint(x);
    return (unsigned short)((u + 0x7fffu + ((u >> 16) & 1u)) >> 16);
}
__device__ __forceinline__ unsigned pack2(float a, float b) {   // -> [bf16(a), bf16(b)]
    unsigned ua = __float_as_uint(a) + 0x8000u;   // round-half-up (0.5 ulp)
    unsigned ub = __float_as_uint(b) + 0x8000u;
    return __builtin_amdgcn_perm(ub, ua, 0x07060302u);
}

// ---------------------------------------------------------------------------
__global__ void prep_kernel(const float* __restrict__ W0, const float* __restrict__ W1,
                            const float* __restrict__ W2, const float* __restrict__ A1,
                            const float* __restrict__ A2, const float* __restrict__ A3,
                            unsigned short* __restrict__ wtf, unsigned short* __restrict__ wb,
                            float* __restrict__ a1t, float* __restrict__ a2t,
                            float* __restrict__ a3t, float* __restrict__ dg2)
{
    int idx = blockIdx.x * blockDim.x + threadIdx.x;
    const double c0 = 1.0 / sqrt(5376.0);
    const double cl_[3] = { c0, c0 / sqrt(3.0), c0 / sqrt(5.0) };
    // A) wtf[chan][2880] (padded fwd table, zero pads)
    if (idx < 64 * NP) {
        int c = idx / NP, p = idx - c * NP;
        unsigned short val = 0;
        int l = -1, local = 0, mul = 0;
        if (p < 2112)      { local = p;        if (local < 2080) { l = 0; mul = 64; } }
        else if (p < 2688) { local = p - 2112; if (local < 528)  { l = 1; mul = 32; } }
        else               { local = p - 2688; if (local < 136)  { l = 2; mul = 16; } }
        if (l >= 0) {
            int u = 0;
            while ((u + 1) * mul - (u + 1) * u / 2 <= local) u++;
            int v = u + (local - (u * mul - u * (u - 1) / 2));
            const float* W = (l == 0) ? W0 : (l == 1) ? W1 : W2;
            float wv = W[(u * mul + v) * 64 + c];
            if (u != v) wv += W[(v * mul + u) * 64 + c];
            val = f2bf((float)(cl_[l] * wv));
        }
        wtf[(size_t)c * NP + p] = val;
        return;
    }
    idx -= 64 * NP;
    // B) wb[5376][64] full symmetrized (diag doubled)
    if (idx < 5376 * 64) {
        int pair = idx >> 6, c = idx & 63;
        int l, w, v, mul;
        if (pair < 4096)      { l = 0; mul = 64; w = pair >> 6;          v = pair & 63; }
        else if (pair < 5120) { l = 1; mul = 32; w = (pair - 4096) >> 5; v = (pair - 4096) & 31; }
        else                  { l = 2; mul = 16; w = (pair - 5120) >> 4; v = (pair - 5120) & 15; }
        const float* W = (l == 0) ? W0 : (l == 1) ? W1 : W2;
        float val;
        if (v == w) val = (float)(2.0 * cl_[l]) * W[(w * mul + w) * 64 + c];
        else        val = (float)cl_[l] * (W[(w * mul + v) * 64 + c] + W[(v * mul + w) * 64 + c]);
        wb[(size_t)pair * 64 + c] = f2bf(val);
        return;
    }
    idx -= 5376 * 64;
    // C) transposed MLP mats
    if (idx < 3 * 4096) {
        int m = idx >> 12, e = idx & 4095;
        int j = e >> 6, k = e & 63;
        const float* A = (m == 0) ? A1 : (m == 1) ? A2 : A3;
        float* dst     = (m == 0) ? a1t : (m == 1) ? a2t : a3t;
        dst[j * 64 + k] = A[k * 64 + j];
        return;
    }
    idx -= 3 * 4096;
    // D) dg2 = colsum(A3)
    if (idx < 64) {
        float s = 0.f;
        for (int k = 0; k < 64; k++) s += A3[k * 64 + idx];
        dg2[idx] = s;
    }
}

// ---------------------------------------------------------------------------
// forward: static pair value from register array
// ---------------------------------------------------------------------------
template <int P, int NX>
__device__ __forceinline__ float pval(const float (&x)[NX]) {
    constexpr int l = PT.l[P];
    if constexpr (l < 0) {
        return 0.f;
    } else if constexpr (l == 0) {
        return x[PT.u[P]] * x[PT.v[P]];
    } else if constexpr (l == 1) {
        constexpr int u = 3 * PT.u[P], v = 3 * PT.v[P];
        return x[u] * x[v] + x[u + 1] * x[v + 1] + x[u + 2] * x[v + 2];
    } else {
        constexpr int u = 5 * PT.u[P], v = 5 * PT.v[P];
        return x[u] * x[v] + x[u + 1] * x[v + 1] + x[u + 2] * x[v + 2]
             + x[u + 3] * x[v + 3] + x[u + 4] * x[v + 4];
    }
}

// one octet (8 pairs) of P -> Pb, fully compile-time indices
template <int CH, int O, int NX>
__device__ __forceinline__ void p_octet(const float (&xr)[NX],
        unsigned short (&Pb)[64][64], int lane)
{
    uint4 w;
    w.x = pack2(pval<CH * 64 + O * 8 + 0, NX>(xr), pval<CH * 64 + O * 8 + 1, NX>(xr));
    w.y = pack2(pval<CH * 64 + O * 8 + 2, NX>(xr), pval<CH * 64 + O * 8 + 3, NX>(xr));
    w.z = pack2(pval<CH * 64 + O * 8 + 4, NX>(xr), pval<CH * 64 + O * 8 + 5, NX>(xr));
    w.w = pack2(pval<CH * 64 + O * 8 + 6, NX>(xr), pval<CH * 64 + O * 8 + 7, NX>(xr));
    *(uint4*)&Pb[lane][(O ^ (lane & 7)) * 8] = w;
}

template <int CH, int NX, int... Os>
__device__ __forceinline__ void p_octets(std::integer_sequence<int, Os...>,
        const float (&xr)[NX], unsigned short (&Pb)[64][64], int lane)
{
    (p_octet<CH, Os, NX>(xr, Pb, lane), ...);
}

template <int CH, int NX>
__device__ __forceinline__ void fwd_chunk(const float (&xr)[NX],
        unsigned short (&Pb)[64][64], const unsigned short* __restrict__ wtf,
        f4 (&acc)[4][4], int lane, int l15, int quad)
{
    // 1) P compute (regs) -> Pb row (octet-swizzled)
    p_octets<CH, NX>(std::make_integer_sequence<int, 8>{}, xr, Pb, lane);
    __syncthreads();
    // 2) A-frags from Pb, B-frags direct from global, 32 MFMAs
    bf8 a[4][2];
    #pragma unroll
    for (int rt = 0; rt < 4; ++rt) {
        int row = 16 * rt + l15;
        #pragma unroll
        for (int ks = 0; ks < 2; ++ks)
            a[rt][ks] = *(const bf8*)&Pb[row][((ks * 4 + quad) ^ (row & 7)) * 8];
    }
    #pragma unroll
    for (int ct = 0; ct < 4; ++ct) {
        #pragma unroll
        for (int ks = 0; ks < 2; ++ks) {
            bf8 b = *(const bf8*)(wtf + (size_t)(16 * ct + l15) * NP + CH * 64 + ks * 32 + quad * 8);
            #pragma unroll
            for (int rt = 0; rt < 4; ++rt)
                acc[rt][ct] = __builtin_amdgcn_mfma_f32_16x16x32_bf16(a[rt][ks], b, acc[rt][ct], 0, 0, 0);
        }
    }
    __syncthreads();   // protect Pb reuse (WAR)
}

template <int B, int NX, int... Is>
__device__ __forceinline__ void fwd_run(std::integer_sequence<int, Is...>,
        const float (&xr)[NX], unsigned short (&Pb)[64][64],
        const unsigned short* __restrict__ wtf, f4 (&acc)[4][4],
        int lane, int l15, int quad)
{
    (fwd_chunk<B + Is, NX>(xr, Pb, wtf, acc, lane, l15, quad), ...);
}

__global__ __launch_bounds__(64) void fctp_fwd(const float* __restrict__ tin,
        const unsigned short* __restrict__ wtf, float* __restrict__ h, int n)
{
    __shared__ unsigned short Pb[64][64];
    const int lane = threadIdx.x;
    const int l15 = lane & 15, quad = lane >> 4;
    const int s0 = blockIdx.x * 64;
    const int s = s0 + lane;
    const int sld = (s < n) ? s : (n - 1);
    const float* xrow = tin + (size_t)sld * IRR;
    f4 acc[4][4];
    #pragma unroll
    for (int rt = 0; rt < 4; ++rt)
        #pragma unroll
        for (int ct = 0; ct < 4; ++ct) acc[rt][ct] = (f4){0.f, 0.f, 0.f, 0.f};
    {   // phase l0
        float x0[64];
        #pragma unroll
        for (int q = 0; q < 16; ++q) *(float4*)&x0[4 * q] = *(const float4*)(xrow + 4 * q);
        fwd_run<0>(std::make_integer_sequence<int, 33>{}, x0, Pb, wtf, acc, lane, l15, quad);
    }
    {   // phase l1
        float x1[96];
        #pragma unroll
        for (int q = 0; q < 24; ++q) *(float4*)&x1[4 * q] = *(const float4*)(xrow + 64 + 4 * q);
        fwd_run<33>(std::make_integer_sequence<int, 9>{}, x1, Pb, wtf, acc, lane, l15, quad);
    }
    {   // phase l2
        float x2[80];
        #pragma unroll
        for (int q = 0; q < 20; ++q) *(float4*)&x2[4 * q] = *(const float4*)(xrow + 160 + 4 * q);
        fwd_run<42>(std::make_integer_sequence<int, 3>{}, x2, Pb, wtf, acc, lane, l15, quad);
    }
    // epilogue: C row = 16rt + 4quad + r, col = 16ct + l15
    #pragma unroll
    for (int rt = 0; rt < 4; ++rt)
        #pragma unroll
        for (int ct = 0; ct < 4; ++ct)
            #pragma unroll
            for (int r = 0; r < 4; ++r) {
                int row = s0 + 16 * rt + 4 * quad + r;
                if (row < n) h[(size_t)row * 64 + 16 * ct + l15] = acc[rt][ct][r];
            }
}

// ---------------------------------------------------------------------------
// backward: dP^T = Wb_chunk @ dh^T ; consume per-sample with x in fp32 regs.
// ---------------------------------------------------------------------------
__device__ __forceinline__ void bwd_mm(int ch, const unsigned short* __restrict__ wb,
        const bf8 (&bh)[4][2], float (&dProw)[64], float (&dPb)[64][68],
        int lane, int l15, int quad)
{
    f4 dp[4][4];
    #pragma unroll
    for (int rt = 0; rt < 4; ++rt)
        #pragma unroll
        for (int ct = 0; ct < 4; ++ct) dp[rt][ct] = (f4){0.f, 0.f, 0.f, 0.f};
    #pragma unroll
    for (int rt = 0; rt < 4; ++rt) {
        #pragma unroll
        for (int ks = 0; ks < 2; ++ks) {
            bf8 a = *(const bf8*)(wb + (size_t)(ch * 64 + 16 * rt + l15) * 64 + ks * 32 + quad * 8);
            #pragma unroll
            for (int ct = 0; ct < 4; ++ct)
                dp[rt][ct] = __builtin_amdgcn_mfma_f32_16x16x32_bf16(a, bh[ct][ks], dp[rt][ct], 0, 0, 0);
        }
    }
    __syncthreads();   // WAR: previous chunk's dPb reads complete
    // dp[rt][ct][r] = dP^T[pair=16rt+4quad+r][sample=16ct+l15] -> dPb[sample][pair]
    #pragma unroll
    for (int rt = 0; rt < 4; ++rt)
        #pragma unroll
        for (int ct = 0; ct < 4; ++ct) {
            float4 v = make_float4(dp[rt][ct][0], dp[rt][ct][1], dp[rt][ct][2], dp[rt][ct][3]);
            *(float4*)&dPb[16 * ct + l15][16 * rt + 4 * quad] = v;
        }
    __syncthreads();
    #pragma unroll
    for (int q = 0; q < 16; ++q) *(float4*)&dProw[4 * q] = *(const float4*)&dPb[lane][4 * q];
}

__global__ __launch_bounds__(64) void fctp_bwd(const float* __restrict__ tin,
        const unsigned short* __restrict__ wb, const float* __restrict__ dh,
        float* __restrict__ y, int n)
{
    __shared__ unsigned short dhb[64][64];
    __shared__ float dPb[64][68];
    const int lane = threadIdx.x;
    const int l15 = lane & 15, quad = lane >> 4;
    const int s0 = blockIdx.x * 64;
    const int s = s0 + lane;
    const int sld = (s < n) ? s : (n - 1);
    const bool act = s < n;
    // stage dh -> bf16 (octet-swizzled)
    {
        const float* dhp = dh + (size_t)sld * 64;
        #pragma unroll
        for (int o = 0; o < 8; ++o) {
            float4 f0 = *(const float4*)(dhp + 8 * o);
            float4 f1 = *(const float4*)(dhp + 8 * o + 4);
            uint4 w = make_uint4(pack2(f0.x, f0.y), pack2(f0.z, f0.w),
                                 pack2(f1.x, f1.y), pack2(f1.z, f1.w));
            *(uint4*)&dhb[lane][(o ^ (lane & 7)) * 8] = w;
        }
    }
    __syncthreads();
    // persistent B-frags: B[k=chan][col=sample]
    bf8 bh[4][2];
    #pragma unroll
    for (int ct = 0; ct < 4; ++ct) {
        int row = 16 * ct + l15;
        #pragma unroll
        for (int ks = 0; ks < 2; ++ks)
            bh[ct][ks] = *(const bf8*)&dhb[row][((ks * 4 + quad) ^ (row & 7)) * 8];
    }
    const float* xrow = tin + (size_t)sld * IRR;
    float* yrow = y + (size_t)sld * IRR;
    float dProw[64];
    {   // phase l0: chunks 0..63, w = ch
        float x0[64];
        #pragma unroll
        for (int q = 0; q < 16; ++q) *(float4*)&x0[4 * q] = *(const float4*)(xrow + 4 * q);
        for (int ch = 0; ch < 64; ++ch) {
            bwd_mm(ch, wb, bh, dProw, dPb, lane, l15, quad);
            float a0 = 0.f, a1 = 0.f, a2 = 0.f, a3 = 0.f;
            #pragma unroll
            for (int p = 0; p < 64; p += 4) {
                a0 += dProw[p] * x0[p];         a1 += dProw[p + 1] * x0[p + 1];
                a2 += dProw[p + 2] * x0[p + 2]; a3 += dProw[p + 3] * x0[p + 3];
            }
            if (act) yrow[ch] = (a0 + a1) + (a2 + a3);
        }
    }
    {   // phase l1: chunks 64..79, w = 2c1+wi, local col = wi*32 + v
        float x1[96];
        #pragma unroll
        for (int q = 0; q < 24; ++q) *(float4*)&x1[4 * q] = *(const float4*)(xrow + 64 + 4 * q);
        for (int c1 = 0; c1 < 16; ++c1) {
            bwd_mm(64 + c1, wb, bh, dProw, dPb, lane, l15, quad);
            float r[2][3] = {{0.f,0.f,0.f},{0.f,0.f,0.f}};
            #pragma unroll
            for (int v = 0; v < 32; ++v) {
                #pragma unroll
                for (int m = 0; m < 3; ++m) {
                    r[0][m] += dProw[v]      * x1[3 * v + m];
                    r[1][m] += dProw[32 + v] * x1[3 * v + m];
                }
            }
            if (act) {
                #pragma unroll
                for (int wi = 0; wi < 2; ++wi)
                    #pragma unroll
                    for (int m = 0; m < 3; ++m)
                        yrow[64 + (2 * c1 + wi) * 3 + m] = r[wi][m];
            }
        }
    }
    {   // phase l2: chunks 80..83, w = 4c2+t, local col = t*16 + v
        float x2[80];
        #pragma unroll
        for (int q = 0; q < 20; ++q) *(float4*)&x2[4 * q] = *(const float4*)(xrow + 160 + 4 * q);
        for (int c2 = 0; c2 < 4; ++c2) {
            bwd_mm(80 + c2, wb, bh, dProw, dPb, lane, l15, quad);
            float r[4][5] = {};
            #pragma unroll
            for (int v = 0; v < 16; ++v)
                #pragma unroll
                for (int t = 0; t < 4; ++t)
                    #pragma unroll
                    for (int m = 0; m < 5; ++m)
                        r[t][m] += dProw[t * 16 + v] * x2[5 * v + m];
            if (act) {
                #pragma unroll
                for (int t = 0; t < 4; ++t)
                    #pragma unroll
                    for (int m = 0; m < 5; ++m)
                        yrow[160 + (4 * c2 + t) * 5 + m] = r[t][m];
            }
        }
    }
}

// ---------------------------------------------------------------------------
// MLP fwd+bwd (unchanged from round 2 — proven correct).
// ---------------------------------------------------------------------------
__global__ __launch_bounds__(128) void mlp_kernel(
    const float* __restrict__ h, const float* __restrict__ A1,
    const float* __restrict__ A2, const float* __restrict__ a1t,
    const float* __restrict__ a2t, const float* __restrict__ a3t,
    const float* __restrict__ b1, const float* __restrict__ b2,
    const float* __restrict__ b3, const float* __restrict__ dg2,
    float* __restrict__ xout, float* __restrict__ dhout, int n)
{
    __shared__ float hst[64][128];
    __shared__ unsigned short z1b[64][128];
    const int tid = threadIdx.x;
    const int s = blockIdx.x * 128 + tid;
    const bool act = s < n;
    #pragma unroll
    for (int q = 0; q < 16; ++q) {
        float4 v = make_float4(0.f, 0.f, 0.f, 0.f);
        if (act) v = ((const float4*)(h + (size_t)s * 64))[q];
        hst[4 * q + 0][tid] = v.x; hst[4 * q + 1][tid] = v.y;
        hst[4 * q + 2][tid] = v.z; hst[4 * q + 3][tid] = v.w;
    }
    float acc[64];
    #pragma unroll
    for (int k = 0; k < 64; ++k) acc[k] = b1[k];
    #pragma unroll 4
    for (int j = 0; j < 64; ++j) {
        float hj = hst[j][tid];
        const float* r = a1t + j * 64;
        #pragma unroll
        for (int k = 0; k < 64; ++k) acc[k] += hj * r[k];
    }
    #pragma unroll
    for (int k = 0; k < 64; ++k) {
        float z = acc[k];
        z1b[k][tid] = f2bf(z);
        float sg = 1.f / (1.f + __expf(-z));
        hst[k][tid] = z * sg;
    }
    #pragma unroll
    for (int k = 0; k < 64; ++k) acc[k] = b2[k];
    #pragma unroll 4
    for (int j = 0; j < 64; ++j) {
        float gj = hst[j][tid];
        const float* r = a2t + j * 64;
        #pragma unroll
        for (int k = 0; k < 64; ++k) acc[k] += gj * r[k];
    }
    float z2r[64];
    #pragma unroll
    for (int k = 0; k < 64; ++k) {
        z2r[k] = acc[k];
        float sg = 1.f / (1.f + __expf(-acc[k]));
        hst[k][tid] = acc[k] * sg;
    }
    #pragma unroll
    for (int k = 0; k < 64; ++k) acc[k] = b3[k];
    #pragma unroll 4
    for (int j = 0; j < 64; ++j) {
        float gj = hst[j][tid];
        const float* r = a3t + j * 64;
        #pragma unroll
        for (int k = 0; k < 64; ++k) acc[k] += gj * r[k];
    }
    if (act) {
        float4* xo = (float4*)(xout + (size_t)s * 64);
        #pragma unroll
        for (int q = 0; q < 16; ++q)
            xo[q] = make_float4(acc[4 * q], acc[4 * q + 1], acc[4 * q + 2], acc[4 * q + 3]);
    }
    #pragma unroll
    for (int k = 0; k < 64; ++k) {
        float z = z2r[k];
        float sg = 1.f / (1.f + __expf(-z));
        hst[k][tid] = dg2[k] * sg * (1.f + z * (1.f - sg));
    }
    #pragma unroll
    for (int j = 0; j < 64; ++j) acc[j] = 0.f;
    #pragma unroll 4
    for (int k = 0; k < 64; ++k) {
        float d = hst[k][tid];
        const float* r = A2 + k * 64;
        #pragma unroll
        for (int j = 0; j < 64; ++j) acc[j] += d * r[j];
    }
    #pragma unroll
    for (int j = 0; j < 64; ++j) {
        float z = __uint_as_float(((unsigned)z1b[j][tid]) << 16);
        float sg = 1.f / (1.f + __expf(-z));
        hst[j][tid] = acc[j] * sg * (1.f + z * (1.f - sg));
    }
    #pragma unroll
    for (int j = 0; j < 64; ++j) acc[j] = 0.f;
    #pragma unroll 4
    for (int k = 0; k < 64; ++k) {
        float d = hst[k][tid];
        const float* r = A1 + k * 64;
        #pragma unroll
        for (int j = 0; j < 64; ++j) acc[j] += d * r[j];
    }
    if (act) {
        float4* dho = (float4*)(dhout + (size_t)s * 64);
        #pragma unroll
        for (int q = 0; q < 16; ++q)
            dho[q] = make_float4(acc[4 * q], acc[4 * q + 1], acc[4 * q + 2], acc[4 * q + 3]);
    }
}

// ---------------------------------------------------------------------------
extern "C" void kernel_launch(void* const* d_in, const int* in_sizes, int n_in,
                              void* d_out, int out_size, void* d_ws, size_t ws_size,
                              hipStream_t stream)
{
    const float* tin = (const float*)d_in[0];
    const float* W0  = (const float*)d_in[1];
    const float* W1  = (const float*)d_in[2];
    const float* W2  = (const float*)d_in[3];
    const float* A1  = (const float*)d_in[4];
    const float* b1  = (const float*)d_in[5];
    const float* A2  = (const float*)d_in[6];
    const float* b2  = (const float*)d_in[7];
    const float* A3  = (const float*)d_in[8];
    const float* b3  = (const float*)d_in[9];
    float* out = (float*)d_out;
    char* ws   = (char*)d_ws;
    const int n = in_sizes[0] / IRR;

    unsigned short* wtf = (unsigned short*)(ws + B_WTF);
    unsigned short* wb  = (unsigned short*)(ws + B_WB);
    float* a1t  = (float*)(ws + B_A1T);
    float* a2t  = (float*)(ws + B_A2T);
    float* a3t  = (float*)(ws + B_A3T);
    float* dg2  = (float*)(ws + B_DG2);
    float* h    = (float*)(ws + B_H);
    float* dh   = h + (size_t)n * 64;
    float* xout = out;
    float* yout = out + (size_t)n * 64;

    const int total_prep = 64 * NP + 5376 * 64 + 3 * 4096 + 64;
    prep_kernel<<<(total_prep + 255) / 256, 256, 0, stream>>>(W0, W1, W2, A1, A2, A3,
                                                              wtf, wb, a1t, a2t, a3t, dg2);
    const int nb64 = (n + 63) / 64;
    fctp_fwd<<<nb64, 64, 0, stream>>>(tin, wtf, h, n);
    mlp_kernel<<<(n + 127) / 128, 128, 0, stream>>>(h, A1, A2, a1t, a2t, a3t,
                                                    b1, b2, b3, dg2, xout, dh, n);
    fctp_bwd<<<nb64, 64, 0, stream>>>(tin, wb, dh, yout, n);
}